// Round 15
// baseline (150.660 us; speedup 1.0000x reference)
//
#include <hip/hip_runtime.h>
#include <hip/hip_fp16.h>

#define RANK 12
#define RES 192
#define NHW (RES * RES)
#define NF 36
#define ODIM 32
#define TEXW 16            // halfs per texel (12 used + 4 pad) -> 32 B
#define NB 4096            // 16^3 cells
#define SORTB 256          // sort blocks
#define SORTT 1024         // threads per sort block
#define TRB 108            // transpose blocks inside fused pre-kernel
#define LROW 36            // padded row stride (floats): 144 B, 16-B aligned

typedef float f32x4 __attribute__((ext_vector_type(4)));
typedef _Float16 h2 __attribute__((ext_vector_type(2)));

__device__ __forceinline__ float fdot2(h2 a, h2 b, float c) {
#if __has_builtin(__builtin_amdgcn_fdot2)
    return __builtin_amdgcn_fdot2(a, b, c, false);
#else
    return c + (float)a.x * (float)b.x + (float)a.y * (float)b.y;
#endif
}

__device__ __forceinline__ int cell16(float x, float y, float z) {
    int qx = min(15, max(0, (int)(x * 16.0f)));
    int qy = min(15, max(0, (int)(y * 16.0f)));
    int qz = min(15, max(0, (int)(z * 16.0f)));
    return (qz << 8) | (qy << 4) | qx;   // x contiguous -> plane rows contiguous
}

// ---------------------------------------------------------------------------
// Fused pre-pass: blocks [0,TRB) transpose planes -> fp16 texels + pack w;
// blocks [TRB, TRB+SORTB) compute the per-block histogram (u16 matrix).
// ---------------------------------------------------------------------------
__global__ __launch_bounds__(SORTT) void vme_pre(const float* __restrict__ a,
                                                 const float* __restrict__ b,
                                                 const float* __restrict__ c,
                                                 const float* __restrict__ w,
                                                 _Float16* __restrict__ t,
                                                 unsigned* __restrict__ w2u,
                                                 const float* __restrict__ xyz,
                                                 unsigned short* __restrict__ m, int n) {
    if (blockIdx.x < TRB) {
        int idx = blockIdx.x * SORTT + threadIdx.x;
        if (idx < ODIM * NF / 2) {
            int o = idx / (NF / 2), k = idx - o * (NF / 2);
            union { h2 h; unsigned u; } cv;
            cv.h.x = (_Float16)w[o * NF + 2 * k];
            cv.h.y = (_Float16)w[o * NF + 2 * k + 1];
            w2u[idx] = cv.u;
        }
        if (idx >= 3 * NHW) return;
        int p = idx / NHW;
        int yx = idx - p * NHW;
        const float* src = (p == 0) ? a : (p == 1) ? b : c;
        _Float16* dst = t + (size_t)idx * TEXW;
#pragma unroll
        for (int r = 0; r < RANK; ++r) dst[r] = (_Float16)src[(size_t)r * NHW + yx];
#pragma unroll
        for (int r = RANK; r < TEXW; ++r) dst[r] = (_Float16)0.0f;
        return;
    }
    // histogram part
    __shared__ int h[NB];
    int tt = threadIdx.x, bb = blockIdx.x - TRB;
    for (int k = tt; k < NB; k += SORTT) h[k] = 0;
    __syncthreads();
    int P = (n + SORTB - 1) / SORTB;
    int lo = bb * P, hi = min(n, lo + P);
    for (int i = lo + tt; i < hi; i += SORTT) {
        float x = __builtin_nontemporal_load(xyz + 3 * (size_t)i + 0);
        float y = __builtin_nontemporal_load(xyz + 3 * (size_t)i + 1);
        float z = __builtin_nontemporal_load(xyz + 3 * (size_t)i + 2);
        atomicAdd(&h[cell16(x, y, z)], 1);
    }
    __syncthreads();
    for (int k = tt; k < NB; k += SORTT) m[(size_t)bb * NB + k] = (unsigned short)h[k];
}

// ---------------------------------------------------------------------------
// S2: per-bin exclusive scan over blocks (thread-per-bin), in place (u16).
// Raw per-bin totals -> T (scanned later inside scatter).
// ---------------------------------------------------------------------------
__global__ __launch_bounds__(256) void vme_scan_cols(unsigned short* __restrict__ m,
                                                     int* __restrict__ T) {
    int k = blockIdx.x * 256 + threadIdx.x;   // grid = NB/256
    unsigned run = 0;
#pragma unroll 8
    for (int b = 0; b < SORTB; ++b) {
        size_t p = (size_t)b * NB + k;
        unsigned v = m[p];
        m[p] = (unsigned short)run;
        run += v;
    }
    T[k] = (int)run;
}

// ---------------------------------------------------------------------------
// S3: scatter. Block-local exclusive scan of T, then bases = m[b][k]+Tscan[k].
// ---------------------------------------------------------------------------
__global__ __launch_bounds__(SORTT) void vme_scatter(const float* __restrict__ xyz,
                                                     const unsigned short* __restrict__ m,
                                                     const int* __restrict__ T,
                                                     f32x4* __restrict__ sorted, int n) {
    __shared__ int sT[NB];              // 16 KB scanned totals
    __shared__ int part[SORTT];         // 4 KB
    __shared__ int bases[NB];           // 16 KB
    __shared__ int ranks[NB];           // 16 KB
    int t = threadIdx.x, b = blockIdx.x;

    // block-local exclusive scan of T[0..NB)
    {
        int base = t * (NB / SORTT);    // 4 per thread
        int l[NB / SORTT];
        int s = 0;
#pragma unroll
        for (int k = 0; k < NB / SORTT; ++k) { l[k] = T[base + k]; s += l[k]; }
        part[t] = s;
        __syncthreads();
        for (int off = 1; off < SORTT; off <<= 1) {
            int u = part[t];
            int add = (t >= off) ? part[t - off] : 0;
            __syncthreads();
            part[t] = u + add;
            __syncthreads();
        }
        int run = part[t] - s;          // exclusive
#pragma unroll
        for (int k = 0; k < NB / SORTT; ++k) { sT[base + k] = run; run += l[k]; }
    }
    __syncthreads();

    for (int k = t; k < NB; k += SORTT) {
        bases[k] = (int)m[(size_t)b * NB + k] + sT[k];
        ranks[k] = 0;
    }
    __syncthreads();
    int P = (n + SORTB - 1) / SORTB;
    int lo = b * P, hi = min(n, lo + P);
    for (int i = lo + t; i < hi; i += SORTT) {
        float x = __builtin_nontemporal_load(xyz + 3 * (size_t)i + 0);
        float y = __builtin_nontemporal_load(xyz + 3 * (size_t)i + 1);
        float z = __builtin_nontemporal_load(xyz + 3 * (size_t)i + 2);
        int c = cell16(x, y, z);
        int r = atomicAdd(&ranks[c], 1);
        f32x4 v = {x, y, z, __uint_as_float((unsigned)i)};
        sorted[bases[c] + r] = v;
    }
}

// ---------------------------------------------------------------------------
// Main kernel: packed fp16 interp + v_dot2 MLP; two-phase 128-row LDS
// write-transpose (19.4 KB -> 6 blocks/CU via launch_bounds(256,6)); NT row
// stores.
// ---------------------------------------------------------------------------
__global__ __launch_bounds__(256, 6) void vme_main_sorted(const f32x4* __restrict__ sorted,
                                                          const _Float16* __restrict__ tp,
                                                          const unsigned* __restrict__ w2u,
                                                          float* __restrict__ out, int n) {
    __shared__ float lrow[128 * LROW];    // 18432 B
    __shared__ unsigned sidx[256];        // 1 KB
    int tid = threadIdx.x;
    int j = blockIdx.x * 256 + tid;
    bool valid = j < n;

    float acc[ODIM];
#pragma unroll
    for (int o = 0; o < ODIM; ++o) acc[o] = 0.0f;
    unsigned idx = 0xFFFFFFFFu;

    if (valid) {
        f32x4 s = __builtin_nontemporal_load(sorted + j);
        idx = __float_as_uint(s.w);
        float us[3] = {s.x, s.x, s.y};
        float vs[3] = {s.y, s.z, s.z};

        h2 f2[NF / 2];
#pragma unroll
        for (int p = 0; p < 3; ++p) {
            float x = us[p] * (float)(RES - 1);
            float y = vs[p] * (float)(RES - 1);
            x = fminf(fmaxf(x, 0.0f), (float)(RES - 1));
            y = fminf(fmaxf(y, 0.0f), (float)(RES - 1));
            int x0 = (int)x;
            int y0 = (int)y;
            int x1 = min(x0 + 1, RES - 1);
            int y1 = min(y0 + 1, RES - 1);
            float wx = x - (float)x0;
            float wy = y - (float)y0;
            _Float16 hw00 = (_Float16)((1.0f - wx) * (1.0f - wy));
            _Float16 hw01 = (_Float16)(wx * (1.0f - wy));
            _Float16 hw10 = (_Float16)((1.0f - wx) * wy);
            _Float16 hw11 = (_Float16)(wx * wy);
            h2 h00 = {hw00, hw00}, h01 = {hw01, hw01}, h10 = {hw10, hw10}, h11 = {hw11, hw11};

            const _Float16* base = tp + (size_t)p * NHW * TEXW;
            const _Float16* t00 = base + (size_t)(y0 * RES + x0) * TEXW;
            const _Float16* t01 = base + (size_t)(y0 * RES + x1) * TEXW;
            const _Float16* t10 = base + (size_t)(y1 * RES + x0) * TEXW;
            const _Float16* t11 = base + (size_t)(y1 * RES + x1) * TEXW;

            union TexA { uint4 v; h2 h[4]; } a00, a01, a10, a11;
            union TexB { uint2 v; h2 h[2]; } b00, b01, b10, b11;
            a00.v = *(const uint4*)(t00);  b00.v = *(const uint2*)(t00 + 8);
            a01.v = *(const uint4*)(t01);  b01.v = *(const uint2*)(t01 + 8);
            a10.v = *(const uint4*)(t10);  b10.v = *(const uint2*)(t10 + 8);
            a11.v = *(const uint4*)(t11);  b11.v = *(const uint2*)(t11 + 8);

#pragma unroll
            for (int q = 0; q < 4; ++q)
                f2[p * 6 + q] = a00.h[q] * h00 + a01.h[q] * h01 + a10.h[q] * h10 + a11.h[q] * h11;
#pragma unroll
            for (int q = 0; q < 2; ++q)
                f2[p * 6 + 4 + q] = b00.h[q] * h00 + b01.h[q] * h01 + b10.h[q] * h10 + b11.h[q] * h11;
        }

#pragma unroll
        for (int o = 0; o < ODIM; ++o) {
            float sum = 0.0f;
#pragma unroll
            for (int k = 0; k < NF / 2; ++k) {
                union { unsigned u; h2 h; } cv;
                cv.u = w2u[o * (NF / 2) + k];
                sum = fdot2(f2[k], cv.h, sum);
            }
            acc[o] = sum;
        }
    }

    sidx[tid] = idx;
    int c = tid & 7;

    // phase 0: rows [0,128) -- phase 1: rows [128,256)
#pragma unroll
    for (int ph = 0; ph < 2; ++ph) {
        int rbase = ph * 128;
        if ((tid >> 7) == ph) {
            int lr = tid & 127;
#pragma unroll
            for (int q = 0; q < 8; ++q) {
                f32x4 v = {acc[4 * q + 0], acc[4 * q + 1], acc[4 * q + 2], acc[4 * q + 3]};
                *(f32x4*)&lrow[lr * LROW + 4 * q] = v;
            }
        }
        __syncthreads();
        // 128 rows x 8 chunks = 1024 chunk-writes over 256 threads = 4 each
        int r0 = tid >> 3;   // 0..31
#pragma unroll
        for (int rr = 0; rr < 4; ++rr) {
            int lr = r0 + rr * 32;
            unsigned id = sidx[rbase + lr];
            if (id != 0xFFFFFFFFu) {
                f32x4 v = *(const f32x4*)&lrow[lr * LROW + 4 * c];
                __builtin_nontemporal_store(v, (f32x4*)(out + (size_t)id * ODIM + 4 * c));
            }
        }
        __syncthreads();
    }
}

// ---------------------------------------------------------------------------
// Fallbacks (f32 weights)
// ---------------------------------------------------------------------------
__global__ __launch_bounds__(256) void vme_transpose_only(const float* __restrict__ a,
                                                          const float* __restrict__ b,
                                                          const float* __restrict__ c,
                                                          _Float16* __restrict__ t) {
    int idx = blockIdx.x * 256 + threadIdx.x;
    if (idx >= 3 * NHW) return;
    int p = idx / NHW;
    int yx = idx - p * NHW;
    const float* src = (p == 0) ? a : (p == 1) ? b : c;
    _Float16* dst = t + (size_t)idx * TEXW;
#pragma unroll
    for (int r = 0; r < RANK; ++r) dst[r] = (_Float16)src[(size_t)r * NHW + yx];
#pragma unroll
    for (int r = RANK; r < TEXW; ++r) dst[r] = (_Float16)0.0f;
}

__device__ __forceinline__ void decode_texel(const _Float16* __restrict__ tex, float* __restrict__ o) {
    union { uint4 v; _Float16 h[8]; } A;
    union { uint2 v; _Float16 h[4]; } B;
    A.v = *(const uint4*)(tex);
    B.v = *(const uint2*)(tex + 8);
#pragma unroll
    for (int r = 0; r < 8; ++r) o[r] = (float)A.h[r];
#pragma unroll
    for (int r = 0; r < 4; ++r) o[8 + r] = (float)B.h[r];
}

__device__ __forceinline__ void vme_compute_point(float px, float py, float pz,
                                                  const _Float16* __restrict__ tp,
                                                  const float* __restrict__ w,
                                                  float* __restrict__ op) {
    float f[NF];
    float us[3] = {px, px, py};
    float vs[3] = {py, pz, pz};
#pragma unroll
    for (int p = 0; p < 3; ++p) {
        float x = us[p] * (float)(RES - 1);
        float y = vs[p] * (float)(RES - 1);
        x = fminf(fmaxf(x, 0.0f), (float)(RES - 1));
        y = fminf(fmaxf(y, 0.0f), (float)(RES - 1));
        int x0 = (int)x, y0 = (int)y;
        int x1 = min(x0 + 1, RES - 1), y1 = min(y0 + 1, RES - 1);
        float wx = x - (float)x0, wy = y - (float)y0;
        float w00 = (1.0f - wx) * (1.0f - wy), w01 = wx * (1.0f - wy);
        float w10 = (1.0f - wx) * wy, w11 = wx * wy;
        const _Float16* base = tp + (size_t)p * NHW * TEXW;
        float d00[RANK], d01[RANK], d10[RANK], d11[RANK];
        decode_texel(base + (size_t)(y0 * RES + x0) * TEXW, d00);
        decode_texel(base + (size_t)(y0 * RES + x1) * TEXW, d01);
        decode_texel(base + (size_t)(y1 * RES + x0) * TEXW, d10);
        decode_texel(base + (size_t)(y1 * RES + x1) * TEXW, d11);
#pragma unroll
        for (int r = 0; r < RANK; ++r)
            f[p * RANK + r] = w00 * d00[r] + w01 * d01[r] + w10 * d10[r] + w11 * d11[r];
    }
    float acc[ODIM];
#pragma unroll
    for (int o = 0; o < ODIM; ++o) {
        float s = 0.0f;
#pragma unroll
        for (int k = 0; k < NF; ++k) s += f[k] * w[o * NF + k];
        acc[o] = s;
    }
#pragma unroll
    for (int q = 0; q < 8; ++q) {
        f32x4 v = {acc[4 * q + 0], acc[4 * q + 1], acc[4 * q + 2], acc[4 * q + 3]};
        *(f32x4*)(op + 4 * q) = v;
    }
}

__global__ __launch_bounds__(256) void vme_main(const float* __restrict__ xyz,
                                                const _Float16* __restrict__ tp,
                                                const float* __restrict__ w,
                                                float* __restrict__ out, int n) {
    int i = blockIdx.x * 256 + threadIdx.x;
    if (i >= n) return;
    vme_compute_point(xyz[3 * (size_t)i], xyz[3 * (size_t)i + 1], xyz[3 * (size_t)i + 2],
                      tp, w, out + (size_t)i * ODIM);
}

__global__ __launch_bounds__(256) void vme_main_fb(const float* __restrict__ xyz,
                                                   const float* __restrict__ pa,
                                                   const float* __restrict__ pb,
                                                   const float* __restrict__ pc,
                                                   const float* __restrict__ w,
                                                   float* __restrict__ out, int n) {
    int i = blockIdx.x * 256 + threadIdx.x;
    if (i >= n) return;
    float px = xyz[3 * (size_t)i + 0];
    float py = xyz[3 * (size_t)i + 1];
    float pz = xyz[3 * (size_t)i + 2];
    float f[NF];
    float us[3] = {px, px, py};
    float vs[3] = {py, pz, pz};
#pragma unroll
    for (int p = 0; p < 3; ++p) {
        float x = us[p] * (float)(RES - 1);
        float y = vs[p] * (float)(RES - 1);
        x = fminf(fmaxf(x, 0.0f), (float)(RES - 1));
        y = fminf(fmaxf(y, 0.0f), (float)(RES - 1));
        int x0 = (int)x, y0 = (int)y;
        int x1 = min(x0 + 1, RES - 1), y1 = min(y0 + 1, RES - 1);
        float wx = x - (float)x0, wy = y - (float)y0;
        float w00 = (1.0f - wx) * (1.0f - wy), w01 = wx * (1.0f - wy);
        float w10 = (1.0f - wx) * wy, w11 = wx * wy;
        const float* base = (p == 0) ? pa : (p == 1) ? pb : pc;
        int i00 = y0 * RES + x0, i01 = y0 * RES + x1;
        int i10 = y1 * RES + x0, i11 = y1 * RES + x1;
#pragma unroll
        for (int r = 0; r < RANK; ++r) {
            const float* pr = base + (size_t)r * NHW;
            f[p * RANK + r] = w00 * pr[i00] + w01 * pr[i01] + w10 * pr[i10] + w11 * pr[i11];
        }
    }
    float acc[ODIM];
#pragma unroll
    for (int o = 0; o < ODIM; ++o) {
        float s = 0.0f;
#pragma unroll
        for (int k = 0; k < NF; ++k) s += f[k] * w[o * NF + k];
        acc[o] = s;
    }
    float4* op = (float4*)(out + (size_t)i * ODIM);
#pragma unroll
    for (int q = 0; q < 8; ++q)
        op[q] = make_float4(acc[4 * q], acc[4 * q + 1], acc[4 * q + 2], acc[4 * q + 3]);
}

extern "C" void kernel_launch(void* const* d_in, const int* in_sizes, int n_in,
                              void* d_out, int out_size, void* d_ws, size_t ws_size,
                              hipStream_t stream) {
    const float* xyz = (const float*)d_in[0];
    const float* xy  = (const float*)d_in[1];
    const float* xz  = (const float*)d_in[2];
    const float* yz  = (const float*)d_in[3];
    const float* wml = (const float*)d_in[4];
    float* out = (float*)d_out;

    int n = in_sizes[0] / 3;
    int nblk = (n + 255) / 256;
    int tblk = (3 * NHW + 255) / 256;

    const size_t TPB      = (size_t)3 * NHW * TEXW * sizeof(_Float16);  // 3,538,944
    const size_t OFF_W2   = TPB;
    const size_t OFF_HIST = TPB + 4096;
    const size_t OFF_T    = OFF_HIST + (size_t)NB * SORTB * 2;          // 2 MB u16 matrix
    const size_t OFF_SORT = OFF_T + (size_t)NB * 4;
    const size_t WS_SORTED = OFF_SORT + (size_t)n * 16;

    char* ws = (char*)d_ws;

    if (d_ws && ws_size >= WS_SORTED) {
        _Float16*       tp  = (_Float16*)(ws);
        unsigned*       w2u = (unsigned*)(ws + OFF_W2);
        unsigned short* m   = (unsigned short*)(ws + OFF_HIST);
        int*            T   = (int*)(ws + OFF_T);
        f32x4*          srt = (f32x4*)(ws + OFF_SORT);

        vme_pre<<<TRB + SORTB, SORTT, 0, stream>>>(xy, xz, yz, wml, tp, w2u, xyz, m, n);
        vme_scan_cols<<<NB / 256, 256, 0, stream>>>(m, T);
        vme_scatter<<<SORTB, SORTT, 0, stream>>>(xyz, m, T, srt, n);
        vme_main_sorted<<<nblk, 256, 0, stream>>>(srt, tp, w2u, out, n);
    } else if (d_ws && ws_size >= TPB) {
        _Float16* tp = (_Float16*)ws;
        vme_transpose_only<<<tblk, 256, 0, stream>>>(xy, xz, yz, tp);
        vme_main<<<nblk, 256, 0, stream>>>(xyz, tp, wml, out, n);
    } else {
        vme_main_fb<<<nblk, 256, 0, stream>>>(xyz, xy, xz, yz, wml, out, n);
    }
}

// Round 16
// 131.492 us; speedup vs baseline: 1.1458x; 1.1458x over previous
//
#include <hip/hip_runtime.h>
#include <hip/hip_fp16.h>

#define RANK 12
#define RES 192
#define NHW (RES * RES)
#define NF 36
#define ODIM 32
#define TEXW 16            // halfs per texel (12 used + 4 pad) -> 32 B
#define NB 4096            // 16^3 cells
#define SORTB 256          // sort blocks
#define SORTT 1024         // threads per sort block
#define TRB 108            // transpose blocks inside fused pre-kernel
#define LROW 36            // padded row stride (floats): 144 B, 16-B aligned

typedef float f32x4 __attribute__((ext_vector_type(4)));
typedef _Float16 h2 __attribute__((ext_vector_type(2)));

__device__ __forceinline__ float fdot2(h2 a, h2 b, float c) {
#if __has_builtin(__builtin_amdgcn_fdot2)
    return __builtin_amdgcn_fdot2(a, b, c, false);
#else
    return c + (float)a.x * (float)b.x + (float)a.y * (float)b.y;
#endif
}

__device__ __forceinline__ int cell16(float x, float y, float z) {
    int qx = min(15, max(0, (int)(x * 16.0f)));
    int qy = min(15, max(0, (int)(y * 16.0f)));
    int qz = min(15, max(0, (int)(z * 16.0f)));
    return (qz << 8) | (qy << 4) | qx;   // x contiguous -> plane rows contiguous
}

// ---------------------------------------------------------------------------
// Fused pre-pass: blocks [0,TRB) transpose planes -> fp16 texels + pack w;
// blocks [TRB, TRB+SORTB) compute the per-block histogram.
// ---------------------------------------------------------------------------
__global__ __launch_bounds__(SORTT) void vme_pre(const float* __restrict__ a,
                                                 const float* __restrict__ b,
                                                 const float* __restrict__ c,
                                                 const float* __restrict__ w,
                                                 _Float16* __restrict__ t,
                                                 unsigned* __restrict__ w2u,
                                                 const float* __restrict__ xyz,
                                                 int* __restrict__ m, int n) {
    if (blockIdx.x < TRB) {
        int idx = blockIdx.x * SORTT + threadIdx.x;
        if (idx < ODIM * NF / 2) {
            int o = idx / (NF / 2), k = idx - o * (NF / 2);
            union { h2 h; unsigned u; } cv;
            cv.h.x = (_Float16)w[o * NF + 2 * k];
            cv.h.y = (_Float16)w[o * NF + 2 * k + 1];
            w2u[idx] = cv.u;
        }
        if (idx >= 3 * NHW) return;
        int p = idx / NHW;
        int yx = idx - p * NHW;
        const float* src = (p == 0) ? a : (p == 1) ? b : c;
        _Float16* dst = t + (size_t)idx * TEXW;
#pragma unroll
        for (int r = 0; r < RANK; ++r) dst[r] = (_Float16)src[(size_t)r * NHW + yx];
#pragma unroll
        for (int r = RANK; r < TEXW; ++r) dst[r] = (_Float16)0.0f;
        return;
    }
    // histogram part
    __shared__ int h[NB];
    int tt = threadIdx.x, bb = blockIdx.x - TRB;
    for (int k = tt; k < NB; k += SORTT) h[k] = 0;
    __syncthreads();
    int P = (n + SORTB - 1) / SORTB;
    int lo = bb * P, hi = min(n, lo + P);
    for (int i = lo + tt; i < hi; i += SORTT) {
        float x = xyz[3 * (size_t)i + 0];
        float y = xyz[3 * (size_t)i + 1];
        float z = xyz[3 * (size_t)i + 2];
        atomicAdd(&h[cell16(x, y, z)], 1);
    }
    __syncthreads();
    for (int k = tt; k < NB; k += SORTT) m[(size_t)bb * NB + k] = h[k];
}

// ---------------------------------------------------------------------------
// S2: per-bin exclusive scan over blocks (thread-per-bin; coalesced rows).
// Leaves raw per-bin totals in T (scanned later inside scatter).
// ---------------------------------------------------------------------------
__global__ __launch_bounds__(256) void vme_scan_cols(int* __restrict__ m,
                                                     int* __restrict__ T) {
    int k = blockIdx.x * 256 + threadIdx.x;   // grid = NB/256
    int run = 0;
#pragma unroll 8
    for (int b = 0; b < SORTB; ++b) {
        size_t p = (size_t)b * NB + k;
        int v = m[p];
        m[p] = run;
        run += v;
    }
    T[k] = run;
}

// ---------------------------------------------------------------------------
// S3: scatter. Each block first exclusive-scans the raw bin totals T in LDS
// (redundant per block, but trivial), then bases = m[b][k] + Tscan[k].
// ---------------------------------------------------------------------------
__global__ __launch_bounds__(SORTT) void vme_scatter(const float* __restrict__ xyz,
                                                     const int* __restrict__ m,
                                                     const int* __restrict__ T,
                                                     f32x4* __restrict__ sorted, int n) {
    __shared__ int sT[NB];              // 16 KB scanned totals
    __shared__ int part[SORTT];         // 4 KB
    __shared__ int bases[NB];           // 16 KB
    __shared__ int ranks[NB];           // 16 KB
    int t = threadIdx.x, b = blockIdx.x;

    // block-local exclusive scan of T[0..NB)
    {
        int base = t * (NB / SORTT);    // 4 per thread
        int l[NB / SORTT];
        int s = 0;
#pragma unroll
        for (int k = 0; k < NB / SORTT; ++k) { l[k] = T[base + k]; s += l[k]; }
        part[t] = s;
        __syncthreads();
        for (int off = 1; off < SORTT; off <<= 1) {
            int u = part[t];
            int add = (t >= off) ? part[t - off] : 0;
            __syncthreads();
            part[t] = u + add;
            __syncthreads();
        }
        int run = part[t] - s;          // exclusive
#pragma unroll
        for (int k = 0; k < NB / SORTT; ++k) { sT[base + k] = run; run += l[k]; }
    }
    __syncthreads();

    for (int k = t; k < NB; k += SORTT) {
        bases[k] = m[(size_t)b * NB + k] + sT[k];
        ranks[k] = 0;
    }
    __syncthreads();
    int P = (n + SORTB - 1) / SORTB;
    int lo = b * P, hi = min(n, lo + P);
    for (int i = lo + t; i < hi; i += SORTT) {
        float x = xyz[3 * (size_t)i + 0];
        float y = xyz[3 * (size_t)i + 1];
        float z = xyz[3 * (size_t)i + 2];
        int c = cell16(x, y, z);
        int r = atomicAdd(&ranks[c], 1);
        f32x4 v = {x, y, z, __uint_as_float((unsigned)i)};
        sorted[bases[c] + r] = v;
    }
}

// ---------------------------------------------------------------------------
// Main kernel: packed fp16 interp + v_dot2 MLP, LDS write-transpose, NT row
// stores (full 128-B rows per lane-octet -> granules merge; L2 stays clean
// for tap reads).
// ---------------------------------------------------------------------------
__global__ __launch_bounds__(256) void vme_main_sorted(const f32x4* __restrict__ sorted,
                                                       const _Float16* __restrict__ tp,
                                                       const unsigned* __restrict__ w2u,
                                                       float* __restrict__ out, int n) {
    __shared__ float lrow[256 * LROW];    // 36864 B
    __shared__ unsigned sidx[256];        // 1 KB
    int tid = threadIdx.x;
    int j = blockIdx.x * 256 + tid;
    bool valid = j < n;

    float acc[ODIM];
#pragma unroll
    for (int o = 0; o < ODIM; ++o) acc[o] = 0.0f;
    unsigned idx = 0xFFFFFFFFu;

    if (valid) {
        f32x4 s = sorted[j];
        idx = __float_as_uint(s.w);
        float us[3] = {s.x, s.x, s.y};
        float vs[3] = {s.y, s.z, s.z};

        h2 f2[NF / 2];
#pragma unroll
        for (int p = 0; p < 3; ++p) {
            float x = us[p] * (float)(RES - 1);
            float y = vs[p] * (float)(RES - 1);
            x = fminf(fmaxf(x, 0.0f), (float)(RES - 1));
            y = fminf(fmaxf(y, 0.0f), (float)(RES - 1));
            int x0 = (int)x;
            int y0 = (int)y;
            int x1 = min(x0 + 1, RES - 1);
            int y1 = min(y0 + 1, RES - 1);
            float wx = x - (float)x0;
            float wy = y - (float)y0;
            _Float16 hw00 = (_Float16)((1.0f - wx) * (1.0f - wy));
            _Float16 hw01 = (_Float16)(wx * (1.0f - wy));
            _Float16 hw10 = (_Float16)((1.0f - wx) * wy);
            _Float16 hw11 = (_Float16)(wx * wy);
            h2 h00 = {hw00, hw00}, h01 = {hw01, hw01}, h10 = {hw10, hw10}, h11 = {hw11, hw11};

            const _Float16* base = tp + (size_t)p * NHW * TEXW;
            const _Float16* t00 = base + (size_t)(y0 * RES + x0) * TEXW;
            const _Float16* t01 = base + (size_t)(y0 * RES + x1) * TEXW;
            const _Float16* t10 = base + (size_t)(y1 * RES + x0) * TEXW;
            const _Float16* t11 = base + (size_t)(y1 * RES + x1) * TEXW;

            union TexA { uint4 v; h2 h[4]; } a00, a01, a10, a11;
            union TexB { uint2 v; h2 h[2]; } b00, b01, b10, b11;
            a00.v = *(const uint4*)(t00);  b00.v = *(const uint2*)(t00 + 8);
            a01.v = *(const uint4*)(t01);  b01.v = *(const uint2*)(t01 + 8);
            a10.v = *(const uint4*)(t10);  b10.v = *(const uint2*)(t10 + 8);
            a11.v = *(const uint4*)(t11);  b11.v = *(const uint2*)(t11 + 8);

#pragma unroll
            for (int q = 0; q < 4; ++q)
                f2[p * 6 + q] = a00.h[q] * h00 + a01.h[q] * h01 + a10.h[q] * h10 + a11.h[q] * h11;
#pragma unroll
            for (int q = 0; q < 2; ++q)
                f2[p * 6 + 4 + q] = b00.h[q] * h00 + b01.h[q] * h01 + b10.h[q] * h10 + b11.h[q] * h11;
        }

#pragma unroll
        for (int o = 0; o < ODIM; ++o) {
            float sum = 0.0f;
#pragma unroll
            for (int k = 0; k < NF / 2; ++k) {
                union { unsigned u; h2 h; } cv;
                cv.u = w2u[o * (NF / 2) + k];
                sum = fdot2(f2[k], cv.h, sum);
            }
            acc[o] = sum;
        }
    }

    sidx[tid] = idx;
#pragma unroll
    for (int q = 0; q < 8; ++q) {
        f32x4 v = {acc[4 * q + 0], acc[4 * q + 1], acc[4 * q + 2], acc[4 * q + 3]};
        *(f32x4*)&lrow[tid * LROW + 4 * q] = v;
    }
    __syncthreads();

    // cooperative row writes: lane handles chunk c of rows r0, r0+32, ...
    int c = tid & 7;
    int r0 = tid >> 3;      // 0..31
#pragma unroll
    for (int rr = 0; rr < 8; ++rr) {
        int r = r0 + rr * 32;
        unsigned id = sidx[r];
        if (id != 0xFFFFFFFFu) {
            f32x4 v = *(const f32x4*)&lrow[r * LROW + 4 * c];
            __builtin_nontemporal_store(v, (f32x4*)(out + (size_t)id * ODIM + 4 * c));
        }
    }
}

// ---------------------------------------------------------------------------
// Fallbacks (f32 weights)
// ---------------------------------------------------------------------------
__global__ __launch_bounds__(256) void vme_transpose_only(const float* __restrict__ a,
                                                          const float* __restrict__ b,
                                                          const float* __restrict__ c,
                                                          _Float16* __restrict__ t) {
    int idx = blockIdx.x * 256 + threadIdx.x;
    if (idx >= 3 * NHW) return;
    int p = idx / NHW;
    int yx = idx - p * NHW;
    const float* src = (p == 0) ? a : (p == 1) ? b : c;
    _Float16* dst = t + (size_t)idx * TEXW;
#pragma unroll
    for (int r = 0; r < RANK; ++r) dst[r] = (_Float16)src[(size_t)r * NHW + yx];
#pragma unroll
    for (int r = RANK; r < TEXW; ++r) dst[r] = (_Float16)0.0f;
}

__device__ __forceinline__ void decode_texel(const _Float16* __restrict__ tex, float* __restrict__ o) {
    union { uint4 v; _Float16 h[8]; } A;
    union { uint2 v; _Float16 h[4]; } B;
    A.v = *(const uint4*)(tex);
    B.v = *(const uint2*)(tex + 8);
#pragma unroll
    for (int r = 0; r < 8; ++r) o[r] = (float)A.h[r];
#pragma unroll
    for (int r = 0; r < 4; ++r) o[8 + r] = (float)B.h[r];
}

__device__ __forceinline__ void vme_compute_point(float px, float py, float pz,
                                                  const _Float16* __restrict__ tp,
                                                  const float* __restrict__ w,
                                                  float* __restrict__ op) {
    float f[NF];
    float us[3] = {px, px, py};
    float vs[3] = {py, pz, pz};
#pragma unroll
    for (int p = 0; p < 3; ++p) {
        float x = us[p] * (float)(RES - 1);
        float y = vs[p] * (float)(RES - 1);
        x = fminf(fmaxf(x, 0.0f), (float)(RES - 1));
        y = fminf(fmaxf(y, 0.0f), (float)(RES - 1));
        int x0 = (int)x, y0 = (int)y;
        int x1 = min(x0 + 1, RES - 1), y1 = min(y0 + 1, RES - 1);
        float wx = x - (float)x0, wy = y - (float)y0;
        float w00 = (1.0f - wx) * (1.0f - wy), w01 = wx * (1.0f - wy);
        float w10 = (1.0f - wx) * wy, w11 = wx * wy;
        const _Float16* base = tp + (size_t)p * NHW * TEXW;
        float d00[RANK], d01[RANK], d10[RANK], d11[RANK];
        decode_texel(base + (size_t)(y0 * RES + x0) * TEXW, d00);
        decode_texel(base + (size_t)(y0 * RES + x1) * TEXW, d01);
        decode_texel(base + (size_t)(y1 * RES + x0) * TEXW, d10);
        decode_texel(base + (size_t)(y1 * RES + x1) * TEXW, d11);
#pragma unroll
        for (int r = 0; r < RANK; ++r)
            f[p * RANK + r] = w00 * d00[r] + w01 * d01[r] + w10 * d10[r] + w11 * d11[r];
    }
    float acc[ODIM];
#pragma unroll
    for (int o = 0; o < ODIM; ++o) {
        float s = 0.0f;
#pragma unroll
        for (int k = 0; k < NF; ++k) s += f[k] * w[o * NF + k];
        acc[o] = s;
    }
#pragma unroll
    for (int q = 0; q < 8; ++q) {
        f32x4 v = {acc[4 * q + 0], acc[4 * q + 1], acc[4 * q + 2], acc[4 * q + 3]};
        *(f32x4*)(op + 4 * q) = v;
    }
}

__global__ __launch_bounds__(256) void vme_main(const float* __restrict__ xyz,
                                                const _Float16* __restrict__ tp,
                                                const float* __restrict__ w,
                                                float* __restrict__ out, int n) {
    int i = blockIdx.x * 256 + threadIdx.x;
    if (i >= n) return;
    vme_compute_point(xyz[3 * (size_t)i], xyz[3 * (size_t)i + 1], xyz[3 * (size_t)i + 2],
                      tp, w, out + (size_t)i * ODIM);
}

__global__ __launch_bounds__(256) void vme_main_fb(const float* __restrict__ xyz,
                                                   const float* __restrict__ pa,
                                                   const float* __restrict__ pb,
                                                   const float* __restrict__ pc,
                                                   const float* __restrict__ w,
                                                   float* __restrict__ out, int n) {
    int i = blockIdx.x * 256 + threadIdx.x;
    if (i >= n) return;
    float px = xyz[3 * (size_t)i + 0];
    float py = xyz[3 * (size_t)i + 1];
    float pz = xyz[3 * (size_t)i + 2];
    float f[NF];
    float us[3] = {px, px, py};
    float vs[3] = {py, pz, pz};
#pragma unroll
    for (int p = 0; p < 3; ++p) {
        float x = us[p] * (float)(RES - 1);
        float y = vs[p] * (float)(RES - 1);
        x = fminf(fmaxf(x, 0.0f), (float)(RES - 1));
        y = fminf(fmaxf(y, 0.0f), (float)(RES - 1));
        int x0 = (int)x, y0 = (int)y;
        int x1 = min(x0 + 1, RES - 1), y1 = min(y0 + 1, RES - 1);
        float wx = x - (float)x0, wy = y - (float)y0;
        float w00 = (1.0f - wx) * (1.0f - wy), w01 = wx * (1.0f - wy);
        float w10 = (1.0f - wx) * wy, w11 = wx * wy;
        const float* base = (p == 0) ? pa : (p == 1) ? pb : pc;
        int i00 = y0 * RES + x0, i01 = y0 * RES + x1;
        int i10 = y1 * RES + x0, i11 = y1 * RES + x1;
#pragma unroll
        for (int r = 0; r < RANK; ++r) {
            const float* pr = base + (size_t)r * NHW;
            f[p * RANK + r] = w00 * pr[i00] + w01 * pr[i01] + w10 * pr[i10] + w11 * pr[i11];
        }
    }
    float acc[ODIM];
#pragma unroll
    for (int o = 0; o < ODIM; ++o) {
        float s = 0.0f;
#pragma unroll
        for (int k = 0; k < NF; ++k) s += f[k] * w[o * NF + k];
        acc[o] = s;
    }
    float4* op = (float4*)(out + (size_t)i * ODIM);
#pragma unroll
    for (int q = 0; q < 8; ++q)
        op[q] = make_float4(acc[4 * q], acc[4 * q + 1], acc[4 * q + 2], acc[4 * q + 3]);
}

extern "C" void kernel_launch(void* const* d_in, const int* in_sizes, int n_in,
                              void* d_out, int out_size, void* d_ws, size_t ws_size,
                              hipStream_t stream) {
    const float* xyz = (const float*)d_in[0];
    const float* xy  = (const float*)d_in[1];
    const float* xz  = (const float*)d_in[2];
    const float* yz  = (const float*)d_in[3];
    const float* wml = (const float*)d_in[4];
    float* out = (float*)d_out;

    int n = in_sizes[0] / 3;
    int nblk = (n + 255) / 256;
    int tblk = (3 * NHW + 255) / 256;

    const size_t TPB      = (size_t)3 * NHW * TEXW * sizeof(_Float16);  // 3,538,944
    const size_t OFF_W2   = TPB;
    const size_t OFF_HIST = TPB + 4096;
    const size_t OFF_T    = OFF_HIST + (size_t)NB * SORTB * 4;          // 4 MB matrix
    const size_t OFF_SORT = OFF_T + (size_t)NB * 4;
    const size_t WS_SORTED = OFF_SORT + (size_t)n * 16;

    char* ws = (char*)d_ws;

    if (d_ws && ws_size >= WS_SORTED) {
        _Float16* tp   = (_Float16*)(ws);
        unsigned* w2u  = (unsigned*)(ws + OFF_W2);
        int*      m    = (int*)(ws + OFF_HIST);
        int*      T    = (int*)(ws + OFF_T);
        f32x4*    srt  = (f32x4*)(ws + OFF_SORT);

        vme_pre<<<TRB + SORTB, SORTT, 0, stream>>>(xy, xz, yz, wml, tp, w2u, xyz, m, n);
        vme_scan_cols<<<NB / 256, 256, 0, stream>>>(m, T);
        vme_scatter<<<SORTB, SORTT, 0, stream>>>(xyz, m, T, srt, n);
        vme_main_sorted<<<nblk, 256, 0, stream>>>(srt, tp, w2u, out, n);
    } else if (d_ws && ws_size >= TPB) {
        _Float16* tp = (_Float16*)ws;
        vme_transpose_only<<<tblk, 256, 0, stream>>>(xy, xz, yz, tp);
        vme_main<<<nblk, 256, 0, stream>>>(xyz, tp, wml, out, n);
    } else {
        vme_main_fb<<<nblk, 256, 0, stream>>>(xyz, xy, xz, yz, wml, out, n);
    }
}